// Round 3
// baseline (369.158 us; speedup 1.0000x reference)
//
#include <hip/hip_runtime.h>
#include <cstdint>

#define N_NODES 50000
#define N_EDGES 800000
#define DIM 64
#define HIDDEN 256
#define NB 64   // nodes per MLP block
#define KC 16   // k-chunk rows of W1 staged in LDS
#define JC 32   // j-chunk rows of W2 staged in LDS
#define SCAN_T 1024

// ---------------------------------------------------------------------------
// CSR build: histogram -> scan -> fill
// ---------------------------------------------------------------------------
__global__ __launch_bounds__(256)
void hist_kernel(const int* __restrict__ dst, int* __restrict__ counts) {
    int e = blockIdx.x * 256 + threadIdx.x;
    if (e < N_EDGES) atomicAdd(&counts[dst[e]], 1);
}

__global__ __launch_bounds__(SCAN_T)
void scan_kernel(const int* __restrict__ counts,
                 int* __restrict__ row_ptr,
                 int* __restrict__ wptr) {
    __shared__ int part[SCAN_T];
    const int t = threadIdx.x;
    const int CH = (N_NODES + SCAN_T - 1) / SCAN_T;  // 49
    const int base = t * CH;
    int sum = 0;
    for (int i = 0; i < CH; ++i) {
        int idx = base + i;
        if (idx < N_NODES) sum += counts[idx];
    }
    part[t] = sum;
    __syncthreads();
    // Hillis-Steele inclusive scan over the 1024 partials
    for (int off = 1; off < SCAN_T; off <<= 1) {
        int v = (t >= off) ? part[t - off] : 0;
        __syncthreads();
        part[t] += v;
        __syncthreads();
    }
    int run = (t == 0) ? 0 : part[t - 1];
    for (int i = 0; i < CH; ++i) {
        int idx = base + i;
        if (idx < N_NODES) {
            row_ptr[idx] = run;
            wptr[idx] = run;
            run += counts[idx];
        }
    }
    if (t == SCAN_T - 1) row_ptr[N_NODES] = part[SCAN_T - 1];
}

__global__ __launch_bounds__(256)
void fill_kernel(const int* __restrict__ src, const int* __restrict__ dst,
                 int* __restrict__ wptr, int* __restrict__ csr) {
    int e = blockIdx.x * 256 + threadIdx.x;
    if (e < N_EDGES) {
        int pos = atomicAdd(&wptr[dst[e]], 1);
        csr[pos] = src[e];
    }
}

// ---------------------------------------------------------------------------
// Gather: one wave (64 lanes) per node, lane = feature dim.
// agg[node] = mean of neighbor features, or h[node] if isolated.
// ---------------------------------------------------------------------------
__global__ __launch_bounds__(256)
void gather_kernel(const float* __restrict__ h,
                   const int* __restrict__ row_ptr,
                   const int* __restrict__ csr,
                   float* __restrict__ agg) {
    int node = blockIdx.x * 4 + (threadIdx.x >> 6);
    if (node >= N_NODES) return;
    int d = threadIdx.x & 63;
    int start = row_ptr[node];
    int end = row_ptr[node + 1];
    int degc = end - start;
    float acc = 0.0f;
    int i = start;
    for (; i + 3 < end; i += 4) {
        int s0 = csr[i], s1 = csr[i + 1], s2 = csr[i + 2], s3 = csr[i + 3];
        float v0 = h[s0 * DIM + d];
        float v1 = h[s1 * DIM + d];
        float v2 = h[s2 * DIM + d];
        float v3 = h[s3 * DIM + d];
        acc += (v0 + v1) + (v2 + v3);
    }
    for (; i < end; ++i) acc += h[csr[i] * DIM + d];
    float outv = (degc > 0) ? (acc / (float)degc) : h[node * DIM + d];
    agg[node * DIM + d] = outv;
}

// ---------------------------------------------------------------------------
// Phase 2: fused 2-layer MLP, NB=64 nodes per 256-thread block. (unchanged
// from round 2 except agg now holds the final mean-or-h feature.)
// ---------------------------------------------------------------------------
__global__ __launch_bounds__(256, 2)
void mlp_kernel(const float* __restrict__ h,
                const float* __restrict__ agg,
                const float* __restrict__ W1,
                const float* __restrict__ b1,
                const float* __restrict__ W2,
                const float* __restrict__ b2,
                float* __restrict__ out) {
    __shared__ __align__(16) char lds_raw[73728];
    float* xs   = (float*)lds_raw;             // [128][64], swizzled
    float* w1s  = (float*)(lds_raw + 32768);   // [KC][256]
    float* hidT = (float*)lds_raw;             // [256][64], overlays xs/w1s
    float* w2s  = (float*)(lds_raw + 65536);   // [JC][64]

    const int tid   = threadIdx.x;
    const int node0 = blockIdx.x * NB;

    // ---- build xs = transpose([h | agg]) with XOR swizzle on n ----
    {
        const int d  = tid & 63;
        const int sw = (d & 3) << 3;
        #pragma unroll
        for (int i = 0; i < 16; ++i) {
            int nn = (tid >> 6) + i * 4;
            int g = node0 + nn;
            if (g >= N_NODES) g = N_NODES - 1;
            float hv = h[g * DIM + d];
            float xv = agg[g * DIM + d];
            int nsw = nn ^ sw;
            xs[d * 64 + nsw]        = hv;
            xs[(64 + d) * 64 + nsw] = xv;
        }
    }

    // ---- layer 1: acc1[h][n] ----
    const int hg = tid & 31;
    const int ng = tid >> 5;
    float acc1[8][8];
    #pragma unroll
    for (int a = 0; a < 8; ++a)
        #pragma unroll
        for (int b = 0; b < 8; ++b) acc1[a][b] = 0.0f;

    for (int kc = 0; kc < 128 / KC; ++kc) {
        __syncthreads();
        {
            const float* w1g = W1 + kc * KC * HIDDEN;
            #pragma unroll
            for (int i = 0; i < 4; ++i) {
                int f = tid * 4 + i * 1024;
                *(float4*)&w1s[f] = *(const float4*)&w1g[f];
            }
        }
        __syncthreads();
        #pragma unroll
        for (int kl = 0; kl < KC; ++kl) {
            const int k = kc * KC + kl;
            const int nbase = ((ng ^ (k & 3)) << 3);
            float4 a0 = *(const float4*)&xs[k * 64 + nbase];
            float4 a1 = *(const float4*)&xs[k * 64 + nbase + 4];
            float4 w0 = *(const float4*)&w1s[kl * HIDDEN + hg * 8];
            float4 w1v = *(const float4*)&w1s[kl * HIDDEN + hg * 8 + 4];
            float an[8] = {a0.x, a0.y, a0.z, a0.w, a1.x, a1.y, a1.z, a1.w};
            float wh[8] = {w0.x, w0.y, w0.z, w0.w, w1v.x, w1v.y, w1v.z, w1v.w};
            #pragma unroll
            for (int hh = 0; hh < 8; ++hh)
                #pragma unroll
                for (int nn = 0; nn < 8; ++nn)
                    acc1[hh][nn] = fmaf(wh[hh], an[nn], acc1[hh][nn]);
        }
    }

    // ---- bias + exact GELU, write hidT (overlays xs/w1s) ----
    float4 b1a = *(const float4*)&b1[hg * 8];
    float4 b1b = *(const float4*)&b1[hg * 8 + 4];
    float bv[8] = {b1a.x, b1a.y, b1a.z, b1a.w, b1b.x, b1b.y, b1b.z, b1b.w};
    __syncthreads();
    #pragma unroll
    for (int hh = 0; hh < 8; ++hh) {
        const int j = hg * 8 + hh;
        #pragma unroll
        for (int nn = 0; nn < 8; ++nn) {
            float v = acc1[hh][nn] + bv[hh];
            acc1[hh][nn] = 0.5f * v * (1.0f + erff(v * 0.70710678118654752440f));
        }
        *(float4*)&hidT[j * 64 + ng * 8] =
            make_float4(acc1[hh][0], acc1[hh][1], acc1[hh][2], acc1[hh][3]);
        *(float4*)&hidT[j * 64 + ng * 8 + 4] =
            make_float4(acc1[hh][4], acc1[hh][5], acc1[hh][6], acc1[hh][7]);
    }

    // ---- layer 2: acc2[n][d] ----
    const int dg = tid & 15;
    const int ng2 = tid >> 4;
    float acc2[4][4];
    #pragma unroll
    for (int a = 0; a < 4; ++a)
        #pragma unroll
        for (int b = 0; b < 4; ++b) acc2[a][b] = 0.0f;

    for (int jc = 0; jc < HIDDEN / JC; ++jc) {
        __syncthreads();
        {
            const float* w2g = W2 + jc * JC * DIM;
            #pragma unroll
            for (int i = 0; i < 2; ++i) {
                int f = tid * 4 + i * 1024;
                *(float4*)&w2s[f] = *(const float4*)&w2g[f];
            }
        }
        __syncthreads();
        #pragma unroll
        for (int jl = 0; jl < JC; ++jl) {
            const int j = jc * JC + jl;
            float4 hv = *(const float4*)&hidT[j * 64 + ng2 * 4];
            float4 wv = *(const float4*)&w2s[jl * 64 + dg * 4];
            acc2[0][0] = fmaf(hv.x, wv.x, acc2[0][0]);
            acc2[0][1] = fmaf(hv.x, wv.y, acc2[0][1]);
            acc2[0][2] = fmaf(hv.x, wv.z, acc2[0][2]);
            acc2[0][3] = fmaf(hv.x, wv.w, acc2[0][3]);
            acc2[1][0] = fmaf(hv.y, wv.x, acc2[1][0]);
            acc2[1][1] = fmaf(hv.y, wv.y, acc2[1][1]);
            acc2[1][2] = fmaf(hv.y, wv.z, acc2[1][2]);
            acc2[1][3] = fmaf(hv.y, wv.w, acc2[1][3]);
            acc2[2][0] = fmaf(hv.z, wv.x, acc2[2][0]);
            acc2[2][1] = fmaf(hv.z, wv.y, acc2[2][1]);
            acc2[2][2] = fmaf(hv.z, wv.z, acc2[2][2]);
            acc2[2][3] = fmaf(hv.z, wv.w, acc2[2][3]);
            acc2[3][0] = fmaf(hv.w, wv.x, acc2[3][0]);
            acc2[3][1] = fmaf(hv.w, wv.y, acc2[3][1]);
            acc2[3][2] = fmaf(hv.w, wv.z, acc2[3][2]);
            acc2[3][3] = fmaf(hv.w, wv.w, acc2[3][3]);
        }
    }

    // ---- output ----
    float4 b2v = *(const float4*)&b2[dg * 4];
    #pragma unroll
    for (int nn = 0; nn < 4; ++nn) {
        int node = node0 + ng2 * 4 + nn;
        if (node < N_NODES) {
            float4 o = make_float4(acc2[nn][0] + b2v.x, acc2[nn][1] + b2v.y,
                                   acc2[nn][2] + b2v.z, acc2[nn][3] + b2v.w);
            *(float4*)&out[node * DIM + dg * 4] = o;
        }
    }
}

// ---------------------------------------------------------------------------
extern "C" void kernel_launch(void* const* d_in, const int* in_sizes, int n_in,
                              void* d_out, int out_size, void* d_ws, size_t ws_size,
                              hipStream_t stream) {
    const float* h  = (const float*)d_in[0];
    const int* eidx = (const int*)d_in[1];   // [2, N_EDGES]: src row then dst row
    const float* W1 = (const float*)d_in[2];
    const float* b1 = (const float*)d_in[3];
    const float* W2 = (const float*)d_in[4];
    const float* b2 = (const float*)d_in[5];
    float* out = (float*)d_out;

    const int* src = eidx;
    const int* dst = eidx + N_EDGES;

    // workspace layout
    float* agg    = (float*)d_ws;                       // 3,200,000 floats
    int*   counts = (int*)(agg + (size_t)N_NODES * DIM); // 50,000
    int*   row_ptr = counts + N_NODES;                   // 50,001
    int*   wptr    = row_ptr + N_NODES + 1;              // 50,000
    int*   csr     = wptr + N_NODES;                     // 800,000

    // zero only the histogram counters
    hipMemsetAsync(counts, 0, (size_t)N_NODES * sizeof(int), stream);

    {
        int grid = (N_EDGES + 255) / 256;
        hist_kernel<<<grid, 256, 0, stream>>>(dst, counts);
    }
    scan_kernel<<<1, SCAN_T, 0, stream>>>(counts, row_ptr, wptr);
    {
        int grid = (N_EDGES + 255) / 256;
        fill_kernel<<<grid, 256, 0, stream>>>(src, dst, wptr, csr);
    }
    {
        int grid = (N_NODES + 3) / 4;
        gather_kernel<<<grid, 256, 0, stream>>>(h, row_ptr, csr, agg);
    }
    {
        int grid = (N_NODES + NB - 1) / NB;
        mlp_kernel<<<grid, 256, 0, stream>>>(h, agg, W1, b1, W2, b2, out);
    }
}

// Round 4
// 248.244 us; speedup vs baseline: 1.4871x; 1.4871x over previous
//
#include <hip/hip_runtime.h>
#include <cstdint>

#define N_NODES 50000
#define N_EDGES 800000
#define DIM 64
#define HIDDEN 256
#define NB 64   // nodes per MLP block
#define KC 16   // k-chunk rows of W1 staged in LDS
#define JC 32   // j-chunk rows of W2 staged in LDS
#define CHUNK 1024
#define SBLK ((N_NODES + CHUNK - 1) / CHUNK)   // 49

// ---------------------------------------------------------------------------
// CSR build: histogram -> hierarchical scan -> fill
// ---------------------------------------------------------------------------
__global__ __launch_bounds__(256)
void hist_kernel(const int* __restrict__ dst, int* __restrict__ counts) {
    int e = blockIdx.x * 256 + threadIdx.x;
    if (e < N_EDGES) atomicAdd(&counts[dst[e]], 1);
}

// Pass 1: per-block sums of 1024 counts each.
__global__ __launch_bounds__(256)
void partial_kernel(const int* __restrict__ counts, int* __restrict__ blk_sums) {
    __shared__ int ws[4];
    const int t = threadIdx.x;
    const int base = blockIdx.x * CHUNK + t * 4;
    int s = 0;
    if (base + 3 < N_NODES) {
        int4 c = *(const int4*)&counts[base];
        s = c.x + c.y + c.z + c.w;
    } else {
        #pragma unroll
        for (int i = 0; i < 4; ++i)
            if (base + i < N_NODES) s += counts[base + i];
    }
    #pragma unroll
    for (int off = 32; off; off >>= 1) s += __shfl_down(s, off, 64);
    if ((t & 63) == 0) ws[t >> 6] = s;
    __syncthreads();
    if (t == 0) blk_sums[blockIdx.x] = ws[0] + ws[1] + ws[2] + ws[3];
}

// Pass 2: single-wave exclusive scan of the 49 block sums.
__global__ __launch_bounds__(64)
void scanblk_kernel(const int* __restrict__ blk_sums, int* __restrict__ blk_off) {
    const int t = threadIdx.x;
    int v = (t < SBLK) ? blk_sums[t] : 0;
    int inc = v;
    #pragma unroll
    for (int off = 1; off < 64; off <<= 1) {
        int u = __shfl_up(inc, off, 64);
        if (t >= off) inc += u;
    }
    if (t < SBLK) blk_off[t] = inc - v;
}

// Pass 3: in-block exclusive scan + block offset -> row_ptr / wptr.
__global__ __launch_bounds__(256)
void scan2_kernel(const int* __restrict__ counts, const int* __restrict__ blk_off,
                  int* __restrict__ row_ptr, int* __restrict__ wptr) {
    __shared__ int ws[4];
    const int t = threadIdx.x;
    const int base = blockIdx.x * CHUNK + t * 4;
    int c0 = 0, c1 = 0, c2 = 0, c3 = 0;
    if (base + 3 < N_NODES) {
        int4 c = *(const int4*)&counts[base];
        c0 = c.x; c1 = c.y; c2 = c.z; c3 = c.w;
    } else {
        if (base     < N_NODES) c0 = counts[base];
        if (base + 1 < N_NODES) c1 = counts[base + 1];
        if (base + 2 < N_NODES) c2 = counts[base + 2];
        if (base + 3 < N_NODES) c3 = counts[base + 3];
    }
    const int s = c0 + c1 + c2 + c3;
    int inc = s;
    const int lane = t & 63;
    #pragma unroll
    for (int off = 1; off < 64; off <<= 1) {
        int u = __shfl_up(inc, off, 64);
        if (lane >= off) inc += u;
    }
    if (lane == 63) ws[t >> 6] = inc;
    __syncthreads();
    const int w = t >> 6;
    int woff = 0;
    if (w > 0) woff += ws[0];
    if (w > 1) woff += ws[1];
    if (w > 2) woff += ws[2];
    int ex = blk_off[blockIdx.x] + woff + (inc - s);
    const int p0 = ex, p1 = ex + c0, p2 = p1 + c1, p3 = p2 + c2;
    if (base     < N_NODES) { row_ptr[base]     = p0; wptr[base]     = p0; }
    if (base + 1 < N_NODES) { row_ptr[base + 1] = p1; wptr[base + 1] = p1; }
    if (base + 2 < N_NODES) { row_ptr[base + 2] = p2; wptr[base + 2] = p2; }
    if (base + 3 < N_NODES) { row_ptr[base + 3] = p3; wptr[base + 3] = p3; }
    if (blockIdx.x == 0 && t == 0) row_ptr[N_NODES] = N_EDGES;
}

__global__ __launch_bounds__(256)
void fill_kernel(const int* __restrict__ src, const int* __restrict__ dst,
                 int* __restrict__ wptr, int* __restrict__ csr) {
    int e = blockIdx.x * 256 + threadIdx.x;
    if (e < N_EDGES) {
        int pos = atomicAdd(&wptr[dst[e]], 1);
        csr[pos] = src[e];
    }
}

// ---------------------------------------------------------------------------
// Gather: one wave (64 lanes) per node, lane = feature dim.
// ---------------------------------------------------------------------------
__global__ __launch_bounds__(256)
void gather_kernel(const float* __restrict__ h,
                   const int* __restrict__ row_ptr,
                   const int* __restrict__ csr,
                   float* __restrict__ agg) {
    int node = blockIdx.x * 4 + (threadIdx.x >> 6);
    if (node >= N_NODES) return;
    int d = threadIdx.x & 63;
    int start = row_ptr[node];
    int end = row_ptr[node + 1];
    int degc = end - start;
    float acc = 0.0f;
    int i = start;
    for (; i + 3 < end; i += 4) {
        int s0 = csr[i], s1 = csr[i + 1], s2 = csr[i + 2], s3 = csr[i + 3];
        float v0 = h[s0 * DIM + d];
        float v1 = h[s1 * DIM + d];
        float v2 = h[s2 * DIM + d];
        float v3 = h[s3 * DIM + d];
        acc += (v0 + v1) + (v2 + v3);
    }
    for (; i < end; ++i) acc += h[csr[i] * DIM + d];
    float outv = (degc > 0) ? (acc / (float)degc) : h[node * DIM + d];
    agg[node * DIM + d] = outv;
}

// ---------------------------------------------------------------------------
// Phase 2: fused 2-layer MLP, NB=64 nodes per 256-thread block.
// ---------------------------------------------------------------------------
__global__ __launch_bounds__(256, 2)
void mlp_kernel(const float* __restrict__ h,
                const float* __restrict__ agg,
                const float* __restrict__ W1,
                const float* __restrict__ b1,
                const float* __restrict__ W2,
                const float* __restrict__ b2,
                float* __restrict__ out) {
    __shared__ __align__(16) char lds_raw[73728];
    float* xs   = (float*)lds_raw;             // [128][64], swizzled
    float* w1s  = (float*)(lds_raw + 32768);   // [KC][256]
    float* hidT = (float*)lds_raw;             // [256][64], overlays xs/w1s
    float* w2s  = (float*)(lds_raw + 65536);   // [JC][64]

    const int tid   = threadIdx.x;
    const int node0 = blockIdx.x * NB;

    {
        const int d  = tid & 63;
        const int sw = (d & 3) << 3;
        #pragma unroll
        for (int i = 0; i < 16; ++i) {
            int nn = (tid >> 6) + i * 4;
            int g = node0 + nn;
            if (g >= N_NODES) g = N_NODES - 1;
            float hv = h[g * DIM + d];
            float xv = agg[g * DIM + d];
            int nsw = nn ^ sw;
            xs[d * 64 + nsw]        = hv;
            xs[(64 + d) * 64 + nsw] = xv;
        }
    }

    const int hg = tid & 31;
    const int ng = tid >> 5;
    float acc1[8][8];
    #pragma unroll
    for (int a = 0; a < 8; ++a)
        #pragma unroll
        for (int b = 0; b < 8; ++b) acc1[a][b] = 0.0f;

    for (int kc = 0; kc < 128 / KC; ++kc) {
        __syncthreads();
        {
            const float* w1g = W1 + kc * KC * HIDDEN;
            #pragma unroll
            for (int i = 0; i < 4; ++i) {
                int f = tid * 4 + i * 1024;
                *(float4*)&w1s[f] = *(const float4*)&w1g[f];
            }
        }
        __syncthreads();
        #pragma unroll
        for (int kl = 0; kl < KC; ++kl) {
            const int k = kc * KC + kl;
            const int nbase = ((ng ^ (k & 3)) << 3);
            float4 a0 = *(const float4*)&xs[k * 64 + nbase];
            float4 a1 = *(const float4*)&xs[k * 64 + nbase + 4];
            float4 w0 = *(const float4*)&w1s[kl * HIDDEN + hg * 8];
            float4 w1v = *(const float4*)&w1s[kl * HIDDEN + hg * 8 + 4];
            float an[8] = {a0.x, a0.y, a0.z, a0.w, a1.x, a1.y, a1.z, a1.w};
            float wh[8] = {w0.x, w0.y, w0.z, w0.w, w1v.x, w1v.y, w1v.z, w1v.w};
            #pragma unroll
            for (int hh = 0; hh < 8; ++hh)
                #pragma unroll
                for (int nn = 0; nn < 8; ++nn)
                    acc1[hh][nn] = fmaf(wh[hh], an[nn], acc1[hh][nn]);
        }
    }

    float4 b1a = *(const float4*)&b1[hg * 8];
    float4 b1b = *(const float4*)&b1[hg * 8 + 4];
    float bv[8] = {b1a.x, b1a.y, b1a.z, b1a.w, b1b.x, b1b.y, b1b.z, b1b.w};
    __syncthreads();
    #pragma unroll
    for (int hh = 0; hh < 8; ++hh) {
        const int j = hg * 8 + hh;
        #pragma unroll
        for (int nn = 0; nn < 8; ++nn) {
            float v = acc1[hh][nn] + bv[hh];
            acc1[hh][nn] = 0.5f * v * (1.0f + erff(v * 0.70710678118654752440f));
        }
        *(float4*)&hidT[j * 64 + ng * 8] =
            make_float4(acc1[hh][0], acc1[hh][1], acc1[hh][2], acc1[hh][3]);
        *(float4*)&hidT[j * 64 + ng * 8 + 4] =
            make_float4(acc1[hh][4], acc1[hh][5], acc1[hh][6], acc1[hh][7]);
    }

    const int dg = tid & 15;
    const int ng2 = tid >> 4;
    float acc2[4][4];
    #pragma unroll
    for (int a = 0; a < 4; ++a)
        #pragma unroll
        for (int b = 0; b < 4; ++b) acc2[a][b] = 0.0f;

    for (int jc = 0; jc < HIDDEN / JC; ++jc) {
        __syncthreads();
        {
            const float* w2g = W2 + jc * JC * DIM;
            #pragma unroll
            for (int i = 0; i < 2; ++i) {
                int f = tid * 4 + i * 1024;
                *(float4*)&w2s[f] = *(const float4*)&w2g[f];
            }
        }
        __syncthreads();
        #pragma unroll
        for (int jl = 0; jl < JC; ++jl) {
            const int j = jc * JC + jl;
            float4 hv = *(const float4*)&hidT[j * 64 + ng2 * 4];
            float4 wv = *(const float4*)&w2s[jl * 64 + dg * 4];
            acc2[0][0] = fmaf(hv.x, wv.x, acc2[0][0]);
            acc2[0][1] = fmaf(hv.x, wv.y, acc2[0][1]);
            acc2[0][2] = fmaf(hv.x, wv.z, acc2[0][2]);
            acc2[0][3] = fmaf(hv.x, wv.w, acc2[0][3]);
            acc2[1][0] = fmaf(hv.y, wv.x, acc2[1][0]);
            acc2[1][1] = fmaf(hv.y, wv.y, acc2[1][1]);
            acc2[1][2] = fmaf(hv.y, wv.z, acc2[1][2]);
            acc2[1][3] = fmaf(hv.y, wv.w, acc2[1][3]);
            acc2[2][0] = fmaf(hv.z, wv.x, acc2[2][0]);
            acc2[2][1] = fmaf(hv.z, wv.y, acc2[2][1]);
            acc2[2][2] = fmaf(hv.z, wv.z, acc2[2][2]);
            acc2[2][3] = fmaf(hv.z, wv.w, acc2[2][3]);
            acc2[3][0] = fmaf(hv.w, wv.x, acc2[3][0]);
            acc2[3][1] = fmaf(hv.w, wv.y, acc2[3][1]);
            acc2[3][2] = fmaf(hv.w, wv.z, acc2[3][2]);
            acc2[3][3] = fmaf(hv.w, wv.w, acc2[3][3]);
        }
    }

    float4 b2v = *(const float4*)&b2[dg * 4];
    #pragma unroll
    for (int nn = 0; nn < 4; ++nn) {
        int node = node0 + ng2 * 4 + nn;
        if (node < N_NODES) {
            float4 o = make_float4(acc2[nn][0] + b2v.x, acc2[nn][1] + b2v.y,
                                   acc2[nn][2] + b2v.z, acc2[nn][3] + b2v.w);
            *(float4*)&out[node * DIM + dg * 4] = o;
        }
    }
}

// ---------------------------------------------------------------------------
extern "C" void kernel_launch(void* const* d_in, const int* in_sizes, int n_in,
                              void* d_out, int out_size, void* d_ws, size_t ws_size,
                              hipStream_t stream) {
    const float* h  = (const float*)d_in[0];
    const int* eidx = (const int*)d_in[1];   // [2, N_EDGES]: src row then dst row
    const float* W1 = (const float*)d_in[2];
    const float* b1 = (const float*)d_in[3];
    const float* W2 = (const float*)d_in[4];
    const float* b2 = (const float*)d_in[5];
    float* out = (float*)d_out;

    const int* src = eidx;
    const int* dst = eidx + N_EDGES;

    // workspace layout
    float* agg     = (float*)d_ws;                        // 3,200,000 floats
    int*   counts  = (int*)(agg + (size_t)N_NODES * DIM); // 50,000
    int*   row_ptr = counts + N_NODES;                    // 50,001
    int*   wptr    = row_ptr + N_NODES + 1;               // 50,000
    int*   csr     = wptr + N_NODES;                      // 800,000
    int*   blk_sums = csr + N_EDGES;                      // SBLK
    int*   blk_off  = blk_sums + SBLK;                    // SBLK

    hipMemsetAsync(counts, 0, (size_t)N_NODES * sizeof(int), stream);

    {
        int grid = (N_EDGES + 255) / 256;
        hist_kernel<<<grid, 256, 0, stream>>>(dst, counts);
    }
    partial_kernel<<<SBLK, 256, 0, stream>>>(counts, blk_sums);
    scanblk_kernel<<<1, 64, 0, stream>>>(blk_sums, blk_off);
    scan2_kernel<<<SBLK, 256, 0, stream>>>(counts, blk_off, row_ptr, wptr);
    {
        int grid = (N_EDGES + 255) / 256;
        fill_kernel<<<grid, 256, 0, stream>>>(src, dst, wptr, csr);
    }
    {
        int grid = (N_NODES + 3) / 4;
        gather_kernel<<<grid, 256, 0, stream>>>(h, row_ptr, csr, agg);
    }
    {
        int grid = (N_NODES + NB - 1) / NB;
        mlp_kernel<<<grid, 256, 0, stream>>>(h, agg, W1, b1, W2, b2, out);
    }
}

// Round 5
// 199.359 us; speedup vs baseline: 1.8517x; 1.2452x over previous
//
#include <hip/hip_runtime.h>
#include <cstdint>

#define N_NODES 50000
#define N_EDGES 800000
#define DIM 64
#define HIDDEN 256
#define CHUNK 1024
#define SBLK ((N_NODES + CHUNK - 1) / CHUNK)   // 49

typedef __attribute__((ext_vector_type(8))) short bf16x8;
typedef __attribute__((ext_vector_type(4))) float f32x4;

__device__ __forceinline__ unsigned short bf16_rne(float f) {
    union { float f; uint32_t u; } cv; cv.f = f;
    uint32_t u = cv.u;
    u += 0x7FFFu + ((u >> 16) & 1u);
    return (unsigned short)(u >> 16);
}

// ---------------------------------------------------------------------------
// CSR build: histogram -> hierarchical scan -> fill
// ---------------------------------------------------------------------------
__global__ __launch_bounds__(256)
void hist_kernel(const int* __restrict__ dst, int* __restrict__ counts) {
    int e = blockIdx.x * 256 + threadIdx.x;
    if (e < N_EDGES) atomicAdd(&counts[dst[e]], 1);
}

__global__ __launch_bounds__(256)
void partial_kernel(const int* __restrict__ counts, int* __restrict__ blk_sums) {
    __shared__ int ws[4];
    const int t = threadIdx.x;
    const int base = blockIdx.x * CHUNK + t * 4;
    int s = 0;
    if (base + 3 < N_NODES) {
        int4 c = *(const int4*)&counts[base];
        s = c.x + c.y + c.z + c.w;
    } else {
        #pragma unroll
        for (int i = 0; i < 4; ++i)
            if (base + i < N_NODES) s += counts[base + i];
    }
    #pragma unroll
    for (int off = 32; off; off >>= 1) s += __shfl_down(s, off, 64);
    if ((t & 63) == 0) ws[t >> 6] = s;
    __syncthreads();
    if (t == 0) blk_sums[blockIdx.x] = ws[0] + ws[1] + ws[2] + ws[3];
}

__global__ __launch_bounds__(64)
void scanblk_kernel(const int* __restrict__ blk_sums, int* __restrict__ blk_off) {
    const int t = threadIdx.x;
    int v = (t < SBLK) ? blk_sums[t] : 0;
    int inc = v;
    #pragma unroll
    for (int off = 1; off < 64; off <<= 1) {
        int u = __shfl_up(inc, off, 64);
        if (t >= off) inc += u;
    }
    if (t < SBLK) blk_off[t] = inc - v;
}

__global__ __launch_bounds__(256)
void scan2_kernel(const int* __restrict__ counts, const int* __restrict__ blk_off,
                  int* __restrict__ row_ptr, int* __restrict__ wptr) {
    __shared__ int ws[4];
    const int t = threadIdx.x;
    const int base = blockIdx.x * CHUNK + t * 4;
    int c0 = 0, c1 = 0, c2 = 0, c3 = 0;
    if (base + 3 < N_NODES) {
        int4 c = *(const int4*)&counts[base];
        c0 = c.x; c1 = c.y; c2 = c.z; c3 = c.w;
    } else {
        if (base     < N_NODES) c0 = counts[base];
        if (base + 1 < N_NODES) c1 = counts[base + 1];
        if (base + 2 < N_NODES) c2 = counts[base + 2];
        if (base + 3 < N_NODES) c3 = counts[base + 3];
    }
    const int s = c0 + c1 + c2 + c3;
    int inc = s;
    const int lane = t & 63;
    #pragma unroll
    for (int off = 1; off < 64; off <<= 1) {
        int u = __shfl_up(inc, off, 64);
        if (lane >= off) inc += u;
    }
    if (lane == 63) ws[t >> 6] = inc;
    __syncthreads();
    const int w = t >> 6;
    int woff = 0;
    if (w > 0) woff += ws[0];
    if (w > 1) woff += ws[1];
    if (w > 2) woff += ws[2];
    int ex = blk_off[blockIdx.x] + woff + (inc - s);
    const int p0 = ex, p1 = ex + c0, p2 = p1 + c1, p3 = p2 + c2;
    if (base     < N_NODES) { row_ptr[base]     = p0; wptr[base]     = p0; }
    if (base + 1 < N_NODES) { row_ptr[base + 1] = p1; wptr[base + 1] = p1; }
    if (base + 2 < N_NODES) { row_ptr[base + 2] = p2; wptr[base + 2] = p2; }
    if (base + 3 < N_NODES) { row_ptr[base + 3] = p3; wptr[base + 3] = p3; }
    if (blockIdx.x == 0 && t == 0) row_ptr[N_NODES] = N_EDGES;
}

__global__ __launch_bounds__(256)
void fill_kernel(const int* __restrict__ src, const int* __restrict__ dst,
                 int* __restrict__ wptr, int* __restrict__ csr) {
    int e = blockIdx.x * 256 + threadIdx.x;
    if (e < N_EDGES) {
        int pos = atomicAdd(&wptr[dst[e]], 1);
        csr[pos] = src[e];
    }
}

// ---------------------------------------------------------------------------
// Weight convert+transpose to bf16 N-major: w1t[n][k] (256x128), w2t[d][j] (64x256)
// ---------------------------------------------------------------------------
__global__ __launch_bounds__(256)
void convert_w_kernel(const float* __restrict__ W1, const float* __restrict__ W2,
                      unsigned short* __restrict__ w1t, unsigned short* __restrict__ w2t) {
    int i = blockIdx.x * 256 + threadIdx.x;
    if (i < 128 * 256) {
        int k = i >> 8, n = i & 255;          // W1[k][n]
        w1t[n * 128 + k] = bf16_rne(W1[i]);
    }
    if (i < 256 * 64) {
        int j = i >> 6, d = i & 63;           // W2[j][d]
        w2t[d * 256 + j] = bf16_rne(W2[i]);
    }
}

// ---------------------------------------------------------------------------
// Gather: one wave per node, lane = feature dim. Emits xb = bf16([h | mean_or_h]).
// ---------------------------------------------------------------------------
__global__ __launch_bounds__(256)
void gather_kernel(const float* __restrict__ h,
                   const int* __restrict__ row_ptr,
                   const int* __restrict__ csr,
                   unsigned short* __restrict__ xb) {
    int node = blockIdx.x * 4 + (threadIdx.x >> 6);
    if (node >= N_NODES) return;
    int d = threadIdx.x & 63;
    int start = row_ptr[node];
    int end = row_ptr[node + 1];
    int degc = end - start;
    float hv = h[node * DIM + d];
    float acc = 0.0f;
    int i = start;
    for (; i + 3 < end; i += 4) {
        int s0 = csr[i], s1 = csr[i + 1], s2 = csr[i + 2], s3 = csr[i + 3];
        float v0 = h[s0 * DIM + d];
        float v1 = h[s1 * DIM + d];
        float v2 = h[s2 * DIM + d];
        float v3 = h[s3 * DIM + d];
        acc += (v0 + v1) + (v2 + v3);
    }
    for (; i < end; ++i) acc += h[csr[i] * DIM + d];
    float outv = (degc > 0) ? (acc / (float)degc) : hv;
    xb[node * 128 + d]      = bf16_rne(hv);
    xb[node * 128 + 64 + d] = bf16_rne(outv);
}

// ---------------------------------------------------------------------------
// MFMA MLP: 4 waves/block, 16 nodes/wave.
// L1: A = xb rows (16x128), B = w1t (n-major), 16 n-tiles x 4 k-steps.
// GELU in-reg, hid -> LDS (bf16, padded stride 264), reload as A-frags.
// L2: 4 n-tiles x 8 k-steps.
// ---------------------------------------------------------------------------
__global__ __launch_bounds__(256)
void mlp_mfma_kernel(const unsigned short* __restrict__ xb,
                     const unsigned short* __restrict__ w1t,
                     const unsigned short* __restrict__ w2t,
                     const float* __restrict__ b1,
                     const float* __restrict__ b2,
                     float* __restrict__ out) {
    __shared__ unsigned short hid_lds[4][16][264];

    const int tid = threadIdx.x;
    const int w   = tid >> 6;
    const int l   = tid & 63;
    const int l15 = l & 15;
    const int kg  = l >> 4;                     // 0..3
    const int node_base = blockIdx.x * 64 + w * 16;

    // ---- layer 1 A-fragments (4 k-steps), clamped row ----
    int arow = node_base + l15;
    if (arow >= N_NODES) arow = N_NODES - 1;
    const unsigned short* aptr = xb + (size_t)arow * 128 + kg * 8;
    bf16x8 afrag[4];
    #pragma unroll
    for (int s = 0; s < 4; ++s)
        afrag[s] = *(const bf16x8*)(aptr + s * 32);

    f32x4 acc[16];
    #pragma unroll
    for (int t = 0; t < 16; ++t) acc[t] = f32x4{0.f, 0.f, 0.f, 0.f};

    #pragma unroll
    for (int t = 0; t < 16; ++t) {
        const unsigned short* bptr = w1t + (t * 16 + l15) * 128 + kg * 8;
        #pragma unroll
        for (int s = 0; s < 4; ++s) {
            bf16x8 bfrag = *(const bf16x8*)(bptr + s * 32);
            acc[t] = __builtin_amdgcn_mfma_f32_16x16x32_bf16(afrag[s], bfrag, acc[t], 0, 0, 0);
        }
    }

    // ---- bias + exact GELU -> hid_lds (D layout: row=kg*4+r, col=t*16+l15) ----
    #pragma unroll
    for (int t = 0; t < 16; ++t) {
        float bias = b1[t * 16 + l15];
        #pragma unroll
        for (int r = 0; r < 4; ++r) {
            float v = acc[t][r] + bias;
            float g = 0.5f * v * (1.0f + erff(v * 0.70710678118654752440f));
            hid_lds[w][kg * 4 + r][t * 16 + l15] = bf16_rne(g);
        }
    }
    __syncthreads();

    // ---- layer 2: A-frags from hid_lds (16B contiguous per lane) ----
    bf16x8 a2[8];
    #pragma unroll
    for (int s = 0; s < 8; ++s)
        a2[s] = *(const bf16x8*)&hid_lds[w][l15][s * 32 + kg * 8];

    #pragma unroll
    for (int t = 0; t < 4; ++t) {
        f32x4 acc2 = f32x4{0.f, 0.f, 0.f, 0.f};
        const unsigned short* bptr = w2t + (t * 16 + l15) * 256 + kg * 8;
        #pragma unroll
        for (int s = 0; s < 8; ++s) {
            bf16x8 bfrag = *(const bf16x8*)(bptr + s * 32);
            acc2 = __builtin_amdgcn_mfma_f32_16x16x32_bf16(a2[s], bfrag, acc2, 0, 0, 0);
        }
        float bias = b2[t * 16 + l15];
        #pragma unroll
        for (int r = 0; r < 4; ++r) {
            int node = node_base + kg * 4 + r;
            if (node < N_NODES)
                out[(size_t)node * DIM + t * 16 + l15] = acc2[r] + bias;
        }
    }
}

// ---------------------------------------------------------------------------
extern "C" void kernel_launch(void* const* d_in, const int* in_sizes, int n_in,
                              void* d_out, int out_size, void* d_ws, size_t ws_size,
                              hipStream_t stream) {
    const float* h  = (const float*)d_in[0];
    const int* eidx = (const int*)d_in[1];   // [2, N_EDGES]: src row then dst row
    const float* W1 = (const float*)d_in[2];
    const float* b1 = (const float*)d_in[3];
    const float* W2 = (const float*)d_in[4];
    const float* b2 = (const float*)d_in[5];
    float* out = (float*)d_out;

    const int* src = eidx;
    const int* dst = eidx + N_EDGES;

    // workspace layout
    unsigned short* xb  = (unsigned short*)d_ws;          // 6,400,000
    unsigned short* w1t = xb + (size_t)N_NODES * 128;     // 32,768
    unsigned short* w2t = w1t + 128 * 256;                // 16,384
    int* counts  = (int*)(w2t + 256 * 64);                // 50,000 (byte off 12,898,304: 4-aligned)
    int* row_ptr = counts + N_NODES;                      // 50,001
    int* wptr    = row_ptr + N_NODES + 1;                 // 50,000
    int* csr     = wptr + N_NODES;                        // 800,000
    int* blk_sums = csr + N_EDGES;                        // SBLK
    int* blk_off  = blk_sums + SBLK;                      // SBLK

    hipMemsetAsync(counts, 0, (size_t)N_NODES * sizeof(int), stream);

    convert_w_kernel<<<128, 256, 0, stream>>>(W1, W2, w1t, w2t);
    {
        int grid = (N_EDGES + 255) / 256;
        hist_kernel<<<grid, 256, 0, stream>>>(dst, counts);
    }
    partial_kernel<<<SBLK, 256, 0, stream>>>(counts, blk_sums);
    scanblk_kernel<<<1, 64, 0, stream>>>(blk_sums, blk_off);
    scan2_kernel<<<SBLK, 256, 0, stream>>>(counts, blk_off, row_ptr, wptr);
    {
        int grid = (N_EDGES + 255) / 256;
        fill_kernel<<<grid, 256, 0, stream>>>(src, dst, wptr, csr);
    }
    {
        int grid = (N_NODES + 3) / 4;
        gather_kernel<<<grid, 256, 0, stream>>>(h, row_ptr, csr, xb);
    }
    {
        int grid = (N_NODES + 63) / 64;
        mlp_mfma_kernel<<<grid, 256, 0, stream>>>(xb, w1t, w2t, b1, b2, out);
    }
}

// Round 6
// 185.013 us; speedup vs baseline: 1.9953x; 1.0775x over previous
//
#include <hip/hip_runtime.h>
#include <cstdint>

#define N_NODES 50000
#define N_EDGES 800000
#define DIM 64
#define HIDDEN 256
#define CHUNK 1024
#define SBLK ((N_NODES + CHUNK - 1) / CHUNK)   // 49

typedef __attribute__((ext_vector_type(8))) short bf16x8;
typedef __attribute__((ext_vector_type(4))) float f32x4;

__device__ __forceinline__ unsigned short bf16_rne(float f) {
    union { float f; uint32_t u; } cv; cv.f = f;
    uint32_t u = cv.u;
    u += 0x7FFFu + ((u >> 16) & 1u);
    return (unsigned short)(u >> 16);
}

__device__ __forceinline__ float bf2f(unsigned short us) {
    union { uint32_t u; float f; } cv; cv.u = ((uint32_t)us) << 16;
    return cv.f;
}

// ---------------------------------------------------------------------------
// CSR build: histogram -> hierarchical scan -> fill
// ---------------------------------------------------------------------------
__global__ __launch_bounds__(256)
void hist_kernel(const int* __restrict__ dst, int* __restrict__ counts) {
    int e = blockIdx.x * 256 + threadIdx.x;
    if (e < N_EDGES) atomicAdd(&counts[dst[e]], 1);
}

__global__ __launch_bounds__(256)
void partial_kernel(const int* __restrict__ counts, int* __restrict__ blk_sums) {
    __shared__ int ws[4];
    const int t = threadIdx.x;
    const int base = blockIdx.x * CHUNK + t * 4;
    int s = 0;
    if (base + 3 < N_NODES) {
        int4 c = *(const int4*)&counts[base];
        s = c.x + c.y + c.z + c.w;
    } else {
        #pragma unroll
        for (int i = 0; i < 4; ++i)
            if (base + i < N_NODES) s += counts[base + i];
    }
    #pragma unroll
    for (int off = 32; off; off >>= 1) s += __shfl_down(s, off, 64);
    if ((t & 63) == 0) ws[t >> 6] = s;
    __syncthreads();
    if (t == 0) blk_sums[blockIdx.x] = ws[0] + ws[1] + ws[2] + ws[3];
}

__global__ __launch_bounds__(64)
void scanblk_kernel(const int* __restrict__ blk_sums, int* __restrict__ blk_off) {
    const int t = threadIdx.x;
    int v = (t < SBLK) ? blk_sums[t] : 0;
    int inc = v;
    #pragma unroll
    for (int off = 1; off < 64; off <<= 1) {
        int u = __shfl_up(inc, off, 64);
        if (t >= off) inc += u;
    }
    if (t < SBLK) blk_off[t] = inc - v;
}

__global__ __launch_bounds__(256)
void scan2_kernel(const int* __restrict__ counts, const int* __restrict__ blk_off,
                  int* __restrict__ row_ptr, int* __restrict__ wptr) {
    __shared__ int ws[4];
    const int t = threadIdx.x;
    const int base = blockIdx.x * CHUNK + t * 4;
    int c0 = 0, c1 = 0, c2 = 0, c3 = 0;
    if (base + 3 < N_NODES) {
        int4 c = *(const int4*)&counts[base];
        c0 = c.x; c1 = c.y; c2 = c.z; c3 = c.w;
    } else {
        if (base     < N_NODES) c0 = counts[base];
        if (base + 1 < N_NODES) c1 = counts[base + 1];
        if (base + 2 < N_NODES) c2 = counts[base + 2];
        if (base + 3 < N_NODES) c3 = counts[base + 3];
    }
    const int s = c0 + c1 + c2 + c3;
    int inc = s;
    const int lane = t & 63;
    #pragma unroll
    for (int off = 1; off < 64; off <<= 1) {
        int u = __shfl_up(inc, off, 64);
        if (lane >= off) inc += u;
    }
    if (lane == 63) ws[t >> 6] = inc;
    __syncthreads();
    const int w = t >> 6;
    int woff = 0;
    if (w > 0) woff += ws[0];
    if (w > 1) woff += ws[1];
    if (w > 2) woff += ws[2];
    int ex = blk_off[blockIdx.x] + woff + (inc - s);
    const int p0 = ex, p1 = ex + c0, p2 = p1 + c1, p3 = p2 + c2;
    if (base     < N_NODES) { row_ptr[base]     = p0; wptr[base]     = p0; }
    if (base + 1 < N_NODES) { row_ptr[base + 1] = p1; wptr[base + 1] = p1; }
    if (base + 2 < N_NODES) { row_ptr[base + 2] = p2; wptr[base + 2] = p2; }
    if (base + 3 < N_NODES) { row_ptr[base + 3] = p3; wptr[base + 3] = p3; }
    if (blockIdx.x == 0 && t == 0) row_ptr[N_NODES] = N_EDGES;
}

__global__ __launch_bounds__(256)
void fill_kernel(const int* __restrict__ src, const int* __restrict__ dst,
                 int* __restrict__ wptr, int* __restrict__ csr) {
    int e = blockIdx.x * 256 + threadIdx.x;
    if (e < N_EDGES) {
        int pos = atomicAdd(&wptr[dst[e]], 1);
        csr[pos] = src[e];
    }
}

// ---------------------------------------------------------------------------
// Prep: bf16 conversions. xb h-half from h; w1t[n][k] (256x128); w2t[d][j] (64x256).
// ---------------------------------------------------------------------------
#define PREP_TOTAL (N_NODES * DIM + 128 * 256 + 256 * 64)
__global__ __launch_bounds__(256)
void prep_kernel(const float* __restrict__ h, const float* __restrict__ W1,
                 const float* __restrict__ W2, unsigned short* __restrict__ xb,
                 unsigned short* __restrict__ w1t, unsigned short* __restrict__ w2t) {
    int i = blockIdx.x * 256 + threadIdx.x;
    if (i < N_NODES * DIM) {
        int node = i >> 6, d = i & 63;
        xb[node * 128 + d] = bf16_rne(h[i]);
    } else if (i < N_NODES * DIM + 128 * 256) {
        int j = i - N_NODES * DIM;
        int k = j >> 8, n = j & 255;          // W1[k][n]
        w1t[n * 128 + k] = bf16_rne(W1[j]);
    } else if (i < PREP_TOTAL) {
        int j = i - N_NODES * DIM - 128 * 256;
        int jr = j >> 6, d = j & 63;          // W2[j][d]
        w2t[d * 256 + jr] = bf16_rne(W2[j]);
    }
}

// ---------------------------------------------------------------------------
// Gather: one wave per node, lane = feature dim. Reads bf16 h-half of xb for
// neighbors, writes bf16 mean (or own h) into the agg-half of xb.
// ---------------------------------------------------------------------------
__global__ __launch_bounds__(256)
void gather_kernel(const int* __restrict__ row_ptr,
                   const int* __restrict__ csr,
                   unsigned short* __restrict__ xb) {
    int node = blockIdx.x * 4 + (threadIdx.x >> 6);
    if (node >= N_NODES) return;
    int d = threadIdx.x & 63;
    int start = row_ptr[node];
    int end = row_ptr[node + 1];
    int degc = end - start;
    float acc = 0.0f;
    int i = start;
    for (; i + 3 < end; i += 4) {
        int s0 = csr[i], s1 = csr[i + 1], s2 = csr[i + 2], s3 = csr[i + 3];
        float v0 = bf2f(xb[(size_t)s0 * 128 + d]);
        float v1 = bf2f(xb[(size_t)s1 * 128 + d]);
        float v2 = bf2f(xb[(size_t)s2 * 128 + d]);
        float v3 = bf2f(xb[(size_t)s3 * 128 + d]);
        acc += (v0 + v1) + (v2 + v3);
    }
    for (; i < end; ++i) acc += bf2f(xb[(size_t)csr[i] * 128 + d]);
    unsigned short res;
    if (degc > 0) res = bf16_rne(acc / (float)degc);
    else          res = xb[(size_t)node * 128 + d];
    xb[(size_t)node * 128 + 64 + d] = res;
}

// ---------------------------------------------------------------------------
// MFMA MLP: block = 64 nodes, 4 waves.
// L1: wave w owns hidden slice j in [w*64, w*64+64) for ALL 64 nodes
//     (4 node-tiles x 4 j-tiles x 4 k-steps = 64 MFMA; w1t read once/block).
// GELU in-reg -> hid LDS [64][264] bf16.
// L2: wave w owns output d-tile w for all 64 nodes (4 node-tiles x 8 k-steps).
// ---------------------------------------------------------------------------
__global__ __launch_bounds__(256)
void mlp_mfma_kernel(const unsigned short* __restrict__ xb,
                     const unsigned short* __restrict__ w1t,
                     const unsigned short* __restrict__ w2t,
                     const float* __restrict__ b1v,
                     const float* __restrict__ b2v,
                     float* __restrict__ out) {
    __shared__ unsigned short hid[64][264];

    const int tid = threadIdx.x;
    const int w   = tid >> 6;
    const int l   = tid & 63;
    const int l15 = l & 15;
    const int kg  = l >> 4;                 // 0..3
    const int node0 = blockIdx.x * 64;

    int arow[4];
    #pragma unroll
    for (int nt = 0; nt < 4; ++nt) {
        int r = node0 + nt * 16 + l15;
        arow[nt] = (r < N_NODES) ? r : (N_NODES - 1);
    }

    // ---- layer 1 ----
    f32x4 acc[4][4];   // [node-tile][j-tile]
    #pragma unroll
    for (int a = 0; a < 4; ++a)
        #pragma unroll
        for (int b = 0; b < 4; ++b) acc[a][b] = f32x4{0.f, 0.f, 0.f, 0.f};

    #pragma unroll
    for (int s = 0; s < 4; ++s) {
        const int kofs = s * 32 + kg * 8;
        bf16x8 a[4], b[4];
        #pragma unroll
        for (int nt = 0; nt < 4; ++nt)
            a[nt] = *(const bf16x8*)(xb + (size_t)arow[nt] * 128 + kofs);
        #pragma unroll
        for (int jt = 0; jt < 4; ++jt)
            b[jt] = *(const bf16x8*)(w1t + ((w * 4 + jt) * 16 + l15) * 128 + kofs);
        #pragma unroll
        for (int nt = 0; nt < 4; ++nt)
            #pragma unroll
            for (int jt = 0; jt < 4; ++jt)
                acc[nt][jt] = __builtin_amdgcn_mfma_f32_16x16x32_bf16(
                    a[nt], b[jt], acc[nt][jt], 0, 0, 0);
    }

    // ---- bias + exact GELU -> hid LDS ----
    #pragma unroll
    for (int jt = 0; jt < 4; ++jt) {
        const int jcol = (w * 4 + jt) * 16 + l15;
        float bias = b1v[jcol];
        #pragma unroll
        for (int nt = 0; nt < 4; ++nt) {
            #pragma unroll
            for (int r = 0; r < 4; ++r) {
                float v = acc[nt][jt][r] + bias;
                float g = 0.5f * v * (1.0f + erff(v * 0.70710678118654752440f));
                hid[nt * 16 + kg * 4 + r][jcol] = bf16_rne(g);
            }
        }
    }
    __syncthreads();

    // ---- layer 2: wave w -> d-tile w ----
    f32x4 acc2[4];
    #pragma unroll
    for (int a = 0; a < 4; ++a) acc2[a] = f32x4{0.f, 0.f, 0.f, 0.f};

    #pragma unroll
    for (int s = 0; s < 8; ++s) {
        const int kofs = s * 32 + kg * 8;
        bf16x8 bb = *(const bf16x8*)(w2t + (w * 16 + l15) * 256 + kofs);
        #pragma unroll
        for (int nt = 0; nt < 4; ++nt) {
            bf16x8 aa = *(const bf16x8*)&hid[nt * 16 + l15][kofs];
            acc2[nt] = __builtin_amdgcn_mfma_f32_16x16x32_bf16(aa, bb, acc2[nt], 0, 0, 0);
        }
    }

    float bias2 = b2v[w * 16 + l15];
    #pragma unroll
    for (int nt = 0; nt < 4; ++nt) {
        #pragma unroll
        for (int r = 0; r < 4; ++r) {
            int node = node0 + nt * 16 + kg * 4 + r;
            if (node < N_NODES)
                out[(size_t)node * DIM + w * 16 + l15] = acc2[nt][r] + bias2;
        }
    }
}

// ---------------------------------------------------------------------------
extern "C" void kernel_launch(void* const* d_in, const int* in_sizes, int n_in,
                              void* d_out, int out_size, void* d_ws, size_t ws_size,
                              hipStream_t stream) {
    const float* h  = (const float*)d_in[0];
    const int* eidx = (const int*)d_in[1];   // [2, N_EDGES]: src row then dst row
    const float* W1 = (const float*)d_in[2];
    const float* b1 = (const float*)d_in[3];
    const float* W2 = (const float*)d_in[4];
    const float* b2 = (const float*)d_in[5];
    float* out = (float*)d_out;

    const int* src = eidx;
    const int* dst = eidx + N_EDGES;

    // workspace layout
    unsigned short* xb  = (unsigned short*)d_ws;          // 6,400,000
    unsigned short* w1t = xb + (size_t)N_NODES * 128;     // 32,768
    unsigned short* w2t = w1t + 128 * 256;                // 16,384
    int* counts  = (int*)(w2t + 256 * 64);                // 50,000
    int* row_ptr = counts + N_NODES;                      // 50,001
    int* wptr    = row_ptr + N_NODES + 1;                 // 50,000
    int* csr     = wptr + N_NODES;                        // 800,000
    int* blk_sums = csr + N_EDGES;                        // SBLK
    int* blk_off  = blk_sums + SBLK;                      // SBLK

    hipMemsetAsync(counts, 0, (size_t)N_NODES * sizeof(int), stream);

    prep_kernel<<<(PREP_TOTAL + 255) / 256, 256, 0, stream>>>(h, W1, W2, xb, w1t, w2t);
    {
        int grid = (N_EDGES + 255) / 256;
        hist_kernel<<<grid, 256, 0, stream>>>(dst, counts);
    }
    partial_kernel<<<SBLK, 256, 0, stream>>>(counts, blk_sums);
    scanblk_kernel<<<1, 64, 0, stream>>>(blk_sums, blk_off);
    scan2_kernel<<<SBLK, 256, 0, stream>>>(counts, blk_off, row_ptr, wptr);
    {
        int grid = (N_EDGES + 255) / 256;
        fill_kernel<<<grid, 256, 0, stream>>>(src, dst, wptr, csr);
    }
    {
        int grid = (N_NODES + 3) / 4;
        gather_kernel<<<grid, 256, 0, stream>>>(row_ptr, csr, xb);
    }
    {
        int grid = (N_NODES + 63) / 64;
        mlp_mfma_kernel<<<grid, 256, 0, stream>>>(xb, w1t, w2t, b1, b2, out);
    }
}